// Round 4
// baseline (543.520 us; speedup 1.0000x reference)
//
#include <hip/hip_runtime.h>
#include <hip/hip_cooperative_groups.h>

namespace cg = cooperative_groups;

// CrossCueFusion on MI355X (gfx950) — round 4.
// r3 post-mortem: cooperative launch was rejected (output identical to never-ran;
// no deadlock). Fix: grid-stride stages + occupancy-sized cooperative attempt with
// checked return code + conventional 5-kernel fallback using the SAME stage bodies.

using bf16x8 = __attribute__((ext_vector_type(8))) short;
using f32x4  = __attribute__((ext_vector_type(4))) float;
using f32x16 = __attribute__((ext_vector_type(16))) float;
typedef unsigned short u16;
typedef unsigned int   u32;

__device__ __forceinline__ u16 f2bf(float f) {  // RNE fp32 -> bf16
  u32 u = __builtin_bit_cast(u32, f);
  u = (u + 0x7fffu + ((u >> 16) & 1u)) >> 16;
  return (u16)u;
}
__device__ __forceinline__ float bf2f(u16 v) {
  u32 u = ((u32)v) << 16;
  return __builtin_bit_cast(float, u);
}
__device__ __forceinline__ u32 pktr(float lo, float hi) {  // trunc-pack 2xfp32->bf16x2
  return __builtin_amdgcn_perm(__builtin_bit_cast(u32, hi),
                               __builtin_bit_cast(u32, lo), 0x07060302u);
}
__device__ __forceinline__ f32x4 mfma16(bf16x8 a, bf16x8 b, f32x4 c) {
  return __builtin_amdgcn_mfma_f32_16x16x32_bf16(a, b, c, 0, 0, 0);
}
__device__ __forceinline__ f32x16 mfma32(bf16x8 a, bf16x8 b, f32x16 c) {
  return __builtin_amdgcn_mfma_f32_32x32x16_bf16(a, b, c, 0, 0, 0);
}
__device__ __forceinline__ f32x16 zero16() {
  f32x16 z = {0,0,0,0,0,0,0,0,0,0,0,0,0,0,0,0};
  return z;
}
__device__ __forceinline__ void store4bf(u16* dst, f32x4 v) {
  u32 lo = (u32)f2bf(v[0]) | ((u32)f2bf(v[1]) << 16);
  u32 hi = (u32)f2bf(v[2]) | ((u32)f2bf(v[3]) << 16);
  *(uint2*)dst = make_uint2(lo, hi);
}

struct MegaArgs {
  const float* mono; const float* cv;
  const float* wsrc[13];
  const float *me_b1, *xe_b1, *mr_b1, *me_b2, *xe_b2;
  const float *mq_b, *mk_b, *mv_b, *xq_b, *xk_b, *xv_b;
  const float *mr_b2, *xr_b, *gamma;
  u16 *wConv, *w1x1, *monoT, *cvT, *m1T, *x1T, *r1T;
  u16 *Qm, *Km, *Vm, *Qx, *Kx, *Vx, *Opart;
  float* lpart;
  float* dout;
};

union SLDS {
  u16 tr[64][40];                                        // S0 transpose tile
  struct { u16 Kl[2][64][40]; u16 Vl[2][32][72]; } att;  // S3 (19456 B, max)
  u16 fp[4][16][40];                                     // S2 per-wave feat bounce
  float fin[16][32];                                     // S4 reduced att rows
};

// shared 3x3 conv body: one wave = 16 out px x 32 out co, 9 taps x 2 MFMAs
__device__ __forceinline__ void conv3x3_body(int bxl, int tid,
    const u16* __restrict__ inT, int Wp, const u16* __restrict__ w9,
    const float* __restrict__ bias, u16* __restrict__ out, int outPitch,
    int outOff, int Ho, int tprShift, int stride) {
  int wid = (bxl * 256 + tid) >> 6;
  int lane = tid & 63, ln = lane & 15, q = lane >> 4;
  int y = wid >> tprShift;
  int x0 = (wid & ((1 << tprShift) - 1)) << 4;
  if (y >= Ho) return;
  f32x4 acc0 = *(const f32x4*)(bias + q * 4);
  f32x4 acc1 = *(const f32x4*)(bias + 16 + q * 4);
  const u16* ib = inT + (stride * y * Wp + stride * (x0 + ln)) * 32 + q * 8;
  const u16* wb = w9 + ln * 32 + q * 8;
#pragma unroll
  for (int dy = 0; dy < 3; ++dy)
#pragma unroll
    for (int dx = 0; dx < 3; ++dx) {
      int tap = dy * 3 + dx;
      bf16x8 bf = *(const bf16x8*)(ib + (dy * Wp + dx) * 32);
      acc0 = mfma16(*(const bf16x8*)(wb + tap * 1024), bf, acc0);
      acc1 = mfma16(*(const bf16x8*)(wb + tap * 1024 + 512), bf, acc1);
    }
#pragma unroll
  for (int r = 0; r < 4; ++r) { acc0[r] = fmaxf(acc0[r], 0.f); acc1[r] = fmaxf(acc1[r], 0.f); }
  u16* ob = out + (outOff + y * outPitch + x0 + ln) * 32;
  store4bf(ob + q * 4, acc0);
  store4bf(ob + 16 + q * 4, acc1);
}

// ============== S0: weight prep + border zeros + transpose ==============
__device__ void stage0(const MegaArgs& a, SLDS& lds) {
  int t = threadIdx.x;
  for (int vb = blockIdx.x; vb < 4234; vb += gridDim.x) {
    if (vb < 13) {
      if (vb < 6) {
        const float* s = a.wsrc[vb];
        u16* d = a.wConv + vb * 9216;  // [tap][co][ci]
        for (int i = t; i < 9216; i += 256) {
          int tap = i >> 10, co = (i >> 5) & 31, ci = i & 31;
          d[i] = f2bf(s[co * 288 + ci * 9 + tap]);
        }
      } else {
        const float* s = a.wsrc[vb];
        u16* d = a.w1x1 + (vb - 6) * 1024;
        for (int i = t; i < 1024; i += 256) d[i] = f2bf(s[i]);
      }
    } else if (vb < 138) {
      int zb = vb - 13;
      int buf = zb % 5, blk = zb / 5;
      u16* b; int Hp, Wp;
      switch (buf) {
        case 0: b = a.monoT; Hp = 258; Wp = 514; break;
        case 1: b = a.cvT;   Hp = 258; Wp = 514; break;
        case 2: b = a.m1T;   Hp = 130; Wp = 258; break;
        case 3: b = a.x1T;   Hp = 130; Wp = 258; break;
        default: b = a.r1T;  Hp = 258; Wp = 514; break;
      }
      int id = blk * 256 + t;
      int cell = id >> 2, c8 = (id & 3) << 3;
      if (cell < 2 * (Hp + Wp)) {
        int r, c;
        if (cell < Wp)               { r = 0;                  c = cell; }
        else if (cell < 2 * Wp)      { r = Hp - 1;             c = cell - Wp; }
        else if (cell < 2 * Wp + Hp) { r = cell - 2 * Wp;      c = 0; }
        else                         { r = cell - 2 * Wp - Hp; c = Wp - 1; }
        bf16x8 z = {0, 0, 0, 0, 0, 0, 0, 0};
        *(bf16x8*)&b[(r * Wp + c) * 32 + c8] = z;
      }
    } else {
      int idx = vb - 138;
      int xb = idx & 7, y = (idx >> 3) & 255, z = idx >> 11;
      const float* src = z ? a.cv : a.mono;
      u16* dst = z ? a.cvT : a.monoT;
      int x0 = xb << 6;
      int ci = t >> 3, kx = (t & 7) << 3;
      const float* sp = src + ci * 131072 + y * 512 + x0 + kx;
      float4 p = *(const float4*)sp;
      float4 p2 = *(const float4*)(sp + 4);
      lds.tr[kx + 0][ci] = f2bf(p.x);  lds.tr[kx + 1][ci] = f2bf(p.y);
      lds.tr[kx + 2][ci] = f2bf(p.z);  lds.tr[kx + 3][ci] = f2bf(p.w);
      lds.tr[kx + 4][ci] = f2bf(p2.x); lds.tr[kx + 5][ci] = f2bf(p2.y);
      lds.tr[kx + 6][ci] = f2bf(p2.z); lds.tr[kx + 7][ci] = f2bf(p2.w);
      __syncthreads();
      int x = t >> 2, c8 = (t & 3) << 3;
      bf16x8 v = *(bf16x8*)&lds.tr[x][c8];
      *(bf16x8*)(dst + ((y + 1) * 514 + (x0 + x + 1)) * 32 + c8) = v;
      __syncthreads();
    }
  }
}

// ============== S1: three big convs ==============
__device__ void stage1(const MegaArgs& a) {
  int t = threadIdx.x;
  for (int vb = blockIdx.x; vb < 3072; vb += gridDim.x) {
    if (vb < 512)
      conv3x3_body(vb, t, a.monoT, 514, a.wConv + 0 * 9216, a.me_b1, a.m1T, 258, 259, 128, 4, 2);
    else if (vb < 1024)
      conv3x3_body(vb - 512, t, a.cvT, 514, a.wConv + 2 * 9216, a.xe_b1, a.x1T, 258, 259, 128, 4, 2);
    else
      conv3x3_body(vb - 1024, t, a.monoT, 514, a.wConv + 4 * 9216, a.mr_b1, a.r1T, 514, 515, 256, 5, 1);
  }
}

// ============== S2: feat conv + q/k/v projections ==============
__device__ void stage2(const MegaArgs& a, SLDS& lds) {
  int t = threadIdx.x;
  for (int vb = blockIdx.x; vb < 256; vb += gridDim.x) {
    int branch = vb >> 7;
    int bxl = vb & 127;
    const u16* inT = branch ? a.x1T : a.m1T;
    const u16* w9 = a.wConv + (branch ? 3 : 1) * 9216;
    const float* cb = branch ? a.xe_b2 : a.me_b2;
    int wave = t >> 6, lane = t & 63, ln = lane & 15, q = lane >> 4;
    int wid = bxl * 4 + wave;
    int y = wid >> 3, x0 = (wid & 7) << 4;
    f32x4 acc0 = *(const f32x4*)(cb + q * 4);
    f32x4 acc1 = *(const f32x4*)(cb + 16 + q * 4);
    const u16* ib = inT + (2 * y * 258 + 2 * (x0 + ln)) * 32 + q * 8;
    const u16* wb = w9 + ln * 32 + q * 8;
#pragma unroll
    for (int dy = 0; dy < 3; ++dy)
#pragma unroll
      for (int dx = 0; dx < 3; ++dx) {
        int tap = dy * 3 + dx;
        bf16x8 bf = *(const bf16x8*)(ib + (dy * 258 + dx) * 32);
        acc0 = mfma16(*(const bf16x8*)(wb + tap * 1024), bf, acc0);
        acc1 = mfma16(*(const bf16x8*)(wb + tap * 1024 + 512), bf, acc1);
      }
#pragma unroll
    for (int r = 0; r < 4; ++r) { acc0[r] = fmaxf(acc0[r], 0.f); acc1[r] = fmaxf(acc1[r], 0.f); }
    u16* fpw = &lds.fp[wave][0][0];
    store4bf(fpw + ln * 40 + q * 4, acc0);
    store4bf(fpw + ln * 40 + 16 + q * 4, acc1);
    bf16x8 bfrag = *(const bf16x8*)(fpw + ln * 40 + q * 8);  // same-wave RAW via lgkmcnt
    int p0 = wid * 16;
    const float* qb = branch ? a.xq_b : a.mq_b;
    const float* kb = branch ? a.xk_b : a.mk_b;
    const float* vbias = branch ? a.xv_b : a.mv_b;
    u16* Qd = branch ? a.Qx : a.Qm;
    u16* Kd = branch ? a.Kx : a.Km;
    u16* Vd = branch ? a.Vx : a.Vm;
    int wbase = branch * 3;
#pragma unroll
    for (int pj3 = 0; pj3 < 3; ++pj3) {
      const u16* w = a.w1x1 + (wbase + pj3) * 1024;
      const float* bias = pj3 == 0 ? qb : (pj3 == 1 ? kb : vbias);
      bf16x8 wa0 = *(const bf16x8*)(w + ln * 32 + q * 8);
      bf16x8 wa1 = *(const bf16x8*)(w + (16 + ln) * 32 + q * 8);
      f32x4 c0 = *(const f32x4*)(bias + q * 4);
      f32x4 c1 = *(const f32x4*)(bias + 16 + q * 4);
      c0 = mfma16(wa0, bfrag, c0);
      c1 = mfma16(wa1, bfrag, c1);
      if (pj3 == 0) {
#pragma unroll
        for (int r = 0; r < 4; ++r) { c0[r] *= 1.4426950408889634f; c1[r] *= 1.4426950408889634f; }
      }
      if (pj3 < 2) {
        u16* dst = pj3 == 0 ? Qd : Kd;
        store4bf(dst + (p0 + ln) * 32 + q * 4, c0);
        store4bf(dst + (p0 + ln) * 32 + 16 + q * 4, c1);
      } else {
        int p = p0 + ln;
        int jl = p & 63, jb = p & ~63;
        int pj = jb + (jl >> 5) * 32 + ((jl >> 4) & 1) * 16 + ((jl >> 2) & 1) * 8
               + ((jl >> 3) & 1) * 4 + (jl & 3);
#pragma unroll
        for (int r = 0; r < 4; ++r) {
          Vd[(q * 4 + r) * 8192 + pj] = f2bf(c0[r]);
          Vd[(16 + q * 4 + r) * 8192 + pj] = f2bf(c1[r]);
        }
      }
    }
  }
}

// ============== S3: split-j flash attention ==============
__device__ void stage3(const MegaArgs& a, SLDS& lds) {
  int t = threadIdx.x;
  for (int vb = blockIdx.x; vb < 1024; vb += gridDim.x) {
    int ib64 = vb & 63, sp = (vb >> 6) & 7, att = vb >> 9;
    const u16 *Qp, *Kp, *Vp;
    if (att == 0) { Qp = a.Qm; Kp = a.Km; Vp = a.Vx; }
    else          { Qp = a.Qx; Kp = a.Kx; Vp = a.Vm; }
    int j0 = sp << 10;
    int wave = t >> 6, lane = t & 63, ln = lane & 31, h = lane >> 5;
    int iw = ib64 * 128 + wave * 32;
    bf16x8 qf0 = *(const bf16x8*)(Qp + (iw + ln) * 32 + h * 8);
    bf16x8 qf1 = *(const bf16x8*)(Qp + (iw + ln) * 32 + 16 + h * 8);
    int krow = t >> 2, kcol = (t & 3) << 3;
    int vrow = t >> 3, vcol = (t & 7) << 3;
    const u16* Kg = Kp + j0 * 32;
    const u16* Vg = Vp + j0;
    bf16x8 kn = *(const bf16x8*)(Kg + t * 8);
    bf16x8 vn = *(const bf16x8*)(Vg + vrow * 8192 + vcol);
    *(bf16x8*)&lds.att.Kl[0][krow][kcol] = kn;
    *(bf16x8*)&lds.att.Vl[0][vrow][vcol] = vn;
    f32x16 O = zero16(), lac = zero16();
    const short oneb = 0x3F80;
    const bf16x8 ones = {oneb, oneb, oneb, oneb, oneb, oneb, oneb, oneb};
    for (int jt = 0; jt < 16; ++jt) {
      __syncthreads();
      bool have = (jt + 1) < 16;
      if (have) {
        kn = *(const bf16x8*)(Kg + (jt + 1) * 2048 + t * 8);
        vn = *(const bf16x8*)(Vg + vrow * 8192 + (jt + 1) * 64 + vcol);
      }
      int cur = jt & 1;
      f32x16 s0 = mfma32(*(const bf16x8*)&lds.att.Kl[cur][ln][h * 8], qf0, zero16());
      s0 = mfma32(*(const bf16x8*)&lds.att.Kl[cur][ln][16 + h * 8], qf1, s0);
      f32x16 s1 = mfma32(*(const bf16x8*)&lds.att.Kl[cur][32 + ln][h * 8], qf0, zero16());
      s1 = mfma32(*(const bf16x8*)&lds.att.Kl[cur][32 + ln][16 + h * 8], qf1, s1);
      float e0[16], e1[16];
#pragma unroll
      for (int r = 0; r < 16; ++r) {
        e0[r] = __builtin_amdgcn_exp2f(s0[r]);
        e1[r] = __builtin_amdgcn_exp2f(s1[r]);
      }
      union PF { bf16x8 v; u32 w[4]; } pf[4];
#pragma unroll
      for (int t2 = 0; t2 < 4; ++t2) {
        int base = (t2 & 1) * 8;
        if (t2 < 2) {
#pragma unroll
          for (int p = 0; p < 4; ++p) pf[t2].w[p] = pktr(e0[base + 2 * p], e0[base + 2 * p + 1]);
        } else {
#pragma unroll
          for (int p = 0; p < 4; ++p) pf[t2].w[p] = pktr(e1[base + 2 * p], e1[base + 2 * p + 1]);
        }
      }
#pragma unroll
      for (int t2 = 0; t2 < 4; ++t2) {
        bf16x8 vf = *(const bf16x8*)&lds.att.Vl[cur][ln][t2 * 16 + h * 8];
        O = mfma32(pf[t2].v, vf, O);
        lac = mfma32(pf[t2].v, ones, lac);
      }
      if (have) {
        *(bf16x8*)&lds.att.Kl[1 - cur][krow][kcol] = kn;
        *(bf16x8*)&lds.att.Vl[1 - cur][vrow][vcol] = vn;
      }
    }
    u16* ob = a.Opart + (size_t)(att * 8 + sp) * 262144;
    float* lb = a.lpart + (att * 8 + sp) * 8192;
#pragma unroll
    for (int r = 0; r < 16; ++r) {
      int ig = iw + (r & 3) + 8 * (r >> 2) + 4 * h;
      ob[ig * 32 + ln] = f2bf(O[r]);
      if (ln == 0) lb[ig] = lac[r];
    }
    __syncthreads();  // protect lds.att across grid-stride iterations
  }
}

// ============== S4: split merge + final epilogues ==============
__device__ void stage4(const MegaArgs& a, SLDS& lds) {
  int t = threadIdx.x;
  for (int u = blockIdx.x; u < 1024; u += gridDim.x) {
    int half = u >> 9;
    int tile = u & 511;
    int tx = tile & 7, ty = tile >> 3;
    int rbase = ty * 128 + tx * 16;
    for (int e = t; e < 512; e += 256) {
      int ir = e >> 5, ch = e & 31;
      int gr = rbase + ir;
      float os = 0.f, ls = 0.f;
#pragma unroll
      for (int sp = 0; sp < 8; ++sp) {
        os += bf2f(a.Opart[(size_t)(half * 8 + sp) * 262144 + gr * 32 + ch]);
        ls += a.lpart[(half * 8 + sp) * 8192 + gr];
      }
      lds.fin[ir][ch] = os / ls;
    }
    __syncthreads();
    int wave = t >> 6, lane = t & 63, ln = lane & 15, q = lane >> 4;
    int y = ty * 4 + wave;
    float g = a.gamma[0];
    if (half == 0) {
      const u16* wb = a.wConv + 5 * 9216 + ln * 32 + q * 8;
      f32x4 b0 = *(const f32x4*)(a.mr_b2 + q * 4);
      f32x4 b1 = *(const f32x4*)(a.mr_b2 + 16 + q * 4);
#pragma unroll
      for (int xc = 0; xc < 4; ++xc) {
        int x0 = tx * 64 + xc * 16;
        f32x4 acc0 = b0, acc1 = b1;
        const u16* ib = a.r1T + (y * 514 + x0 + ln) * 32 + q * 8;
#pragma unroll
        for (int dy = 0; dy < 3; ++dy)
#pragma unroll
          for (int dx = 0; dx < 3; ++dx) {
            int tap = dy * 3 + dx;
            bf16x8 bf = *(const bf16x8*)(ib + (dy * 514 + dx) * 32);
            acc0 = mfma16(*(const bf16x8*)(wb + tap * 1024), bf, acc0);
            acc1 = mfma16(*(const bf16x8*)(wb + tap * 1024 + 512), bf, acc1);
          }
        const float* ap = lds.fin[xc * 4 + (ln >> 2)];
        float* ob = a.dout + y * 512 + x0 + ln;
#pragma unroll
        for (int r = 0; r < 4; ++r) {
          int co0 = q * 4 + r, co1 = 16 + q * 4 + r;
          ob[co0 * 131072] = fmaxf(acc0[r], 0.f) + g * ap[co0];
          ob[co1 * 131072] = fmaxf(acc1[r], 0.f) + g * ap[co1];
        }
      }
    } else {
      const u16* w = a.w1x1 + 6 * 1024;
      bf16x8 wa0 = *(const bf16x8*)(w + ln * 32 + q * 8);
      bf16x8 wa1 = *(const bf16x8*)(w + (16 + ln) * 32 + q * 8);
      f32x4 b0 = *(const f32x4*)(a.xr_b + q * 4);
      f32x4 b1 = *(const f32x4*)(a.xr_b + 16 + q * 4);
#pragma unroll
      for (int xc = 0; xc < 4; ++xc) {
        int x0 = tx * 64 + xc * 16;
        bf16x8 bf = *(const bf16x8*)(a.cvT + ((y + 1) * 514 + x0 + ln + 1) * 32 + q * 8);
        f32x4 c0 = mfma16(wa0, bf, b0);
        f32x4 c1 = mfma16(wa1, bf, b1);
        const float* ap = lds.fin[xc * 4 + (ln >> 2)];
        float* ob = a.dout + 32 * 131072 + y * 512 + x0 + ln;
#pragma unroll
        for (int r = 0; r < 4; ++r) {
          int co0 = q * 4 + r, co1 = 16 + q * 4 + r;
          ob[co0 * 131072] = fmaxf(c0[r], 0.f) + g * ap[co0];
          ob[co1 * 131072] = fmaxf(c1[r], 0.f) + g * ap[co1];
        }
      }
    }
    __syncthreads();  // protect lds.fin across grid-stride iterations
  }
}

// ============== cooperative mega-kernel ==============
__global__ void __launch_bounds__(256, 4) k_mega(MegaArgs a) {
  cg::grid_group grid = cg::this_grid();
  __shared__ SLDS lds;
  stage0(a, lds);  grid.sync();
  stage1(a);       grid.sync();
  stage2(a, lds);  grid.sync();
  stage3(a, lds);  grid.sync();
  stage4(a, lds);
}

// ============== conventional fallback kernels (same stage bodies) ==============
__global__ void __launch_bounds__(256, 4) k_s0(MegaArgs a) { __shared__ SLDS lds; stage0(a, lds); }
__global__ void __launch_bounds__(256, 4) k_s1(MegaArgs a) { stage1(a); }
__global__ void __launch_bounds__(256, 4) k_s2(MegaArgs a) { __shared__ SLDS lds; stage2(a, lds); }
__global__ void __launch_bounds__(256, 4) k_s3(MegaArgs a) { __shared__ SLDS lds; stage3(a, lds); }
__global__ void __launch_bounds__(256, 4) k_s4(MegaArgs a) { __shared__ SLDS lds; stage4(a, lds); }

extern "C" void kernel_launch(void* const* d_in, const int* in_sizes, int n_in,
                              void* d_out, int out_size, void* d_ws, size_t ws_size,
                              hipStream_t stream) {
  char* ws = (char*)d_ws;
  MegaArgs m;
  m.mono  = (const float*)d_in[0];
  m.cv    = (const float*)d_in[1];
  m.wsrc[0] = (const float*)d_in[2];   // me_w1
  m.wsrc[1] = (const float*)d_in[4];   // me_w2
  m.wsrc[2] = (const float*)d_in[6];   // xe_w1
  m.wsrc[3] = (const float*)d_in[8];   // xe_w2
  m.wsrc[4] = (const float*)d_in[22];  // mr_w1
  m.wsrc[5] = (const float*)d_in[24];  // mr_w2
  m.wsrc[6] = (const float*)d_in[10];  // mq_w
  m.wsrc[7] = (const float*)d_in[12];  // mk_w
  m.wsrc[8] = (const float*)d_in[14];  // mv_w
  m.wsrc[9] = (const float*)d_in[16];  // xq_w
  m.wsrc[10] = (const float*)d_in[18]; // xk_w
  m.wsrc[11] = (const float*)d_in[20]; // xv_w
  m.wsrc[12] = (const float*)d_in[26]; // xr_w
  m.me_b1 = (const float*)d_in[3];
  m.me_b2 = (const float*)d_in[5];
  m.xe_b1 = (const float*)d_in[7];
  m.xe_b2 = (const float*)d_in[9];
  m.mq_b  = (const float*)d_in[11];
  m.mk_b  = (const float*)d_in[13];
  m.mv_b  = (const float*)d_in[15];
  m.xq_b  = (const float*)d_in[17];
  m.xk_b  = (const float*)d_in[19];
  m.xv_b  = (const float*)d_in[21];
  m.mr_b1 = (const float*)d_in[23];
  m.mr_b2 = (const float*)d_in[25];
  m.xr_b  = (const float*)d_in[27];
  m.gamma = (const float*)d_in[28];
  m.wConv = (u16*)(ws + 0);          // 6 * [9][32][32] bf16
  m.w1x1  = (u16*)(ws + 110592);     // 7 * [32][32] bf16
  m.monoT = (u16*)(ws + 124928);     // [258][514][32] bf16 (dead after S1)
  m.Opart = (u16*)(ws + 124928);     // [2][8][8192][32] bf16 — aliases monoT
  m.cvT   = (u16*)(ws + 8612096);    // [258][514][32]
  m.m1T   = (u16*)(ws + 17099264);   // [130][258][32]
  m.x1T   = (u16*)(ws + 19245824);
  m.r1T   = (u16*)(ws + 21392384);   // [258][514][32]
  m.Qm    = (u16*)(ws + 30928128);   // [8192][32]
  m.Km    = (u16*)(ws + 31452416);
  m.Vm    = (u16*)(ws + 31976704);   // [32][8192] pi-permuted
  m.Qx    = (u16*)(ws + 32500992);
  m.Kx    = (u16*)(ws + 33025280);
  m.Vx    = (u16*)(ws + 33549568);
  m.lpart = (float*)(ws + 36171008); // [2][8][8192] fp32
  m.dout  = (float*)d_out;

  // Attempt cooperative mega-kernel at an occupancy-validated grid size.
  hipError_t err = hipErrorUnknown;
  int occ = 0;
  if (hipOccupancyMaxActiveBlocksPerMultiprocessor(&occ, k_mega, 256, 0) == hipSuccess &&
      occ > 0) {
    int gridB = occ * 256;           // 256 CUs on MI355X
    if (gridB > 1024) gridB = 1024;  // no benefit past the work decomposition
    void* kargs[] = { (void*)&m };
    err = hipLaunchCooperativeKernel((const void*)k_mega, dim3(gridB), dim3(256),
                                     kargs, 0, stream);
  }
  if (err != hipSuccess) {
    // Fallback: same stages, 5 conventional dispatches.
    k_s0<<<4234, 256, 0, stream>>>(m);
    k_s1<<<3072, 256, 0, stream>>>(m);
    k_s2<<<256,  256, 0, stream>>>(m);
    k_s3<<<1024, 256, 0, stream>>>(m);
    k_s4<<<1024, 256, 0, stream>>>(m);
  }
}

// Round 5
// 214.851 us; speedup vs baseline: 2.5298x; 2.5298x over previous
//
#include <hip/hip_runtime.h>

// CrossCueFusion on MI355X (gfx950) — round 5.
// r4 post-mortem: cooperative grid.sync() costs ~125µs each on gfx950 (4 syncs
// ~500µs of idle) — unusable. The fused stage logic itself is VERIFIED correct
// (r4 passed, absmax 0.0156). This round: same 5 stage bodies as conventional
// dispatches (5 launches vs r2's 7), per-stage launch bounds.
//   S0 weight prep + border zero + NCHW->HWC transpose
//   S1 three big 3x3 convs
//   S2 feat conv + q/k/v projections (LDS bounce, no feat buffers)
//   S3 split-j flash attention (transposed-score, P in-register, l via ones-MFMA)
//   S4 split merge + final conv/1x1 epilogues -> d_out

using bf16x8 = __attribute__((ext_vector_type(8))) short;
using f32x4  = __attribute__((ext_vector_type(4))) float;
using f32x16 = __attribute__((ext_vector_type(16))) float;
typedef unsigned short u16;
typedef unsigned int   u32;

__device__ __forceinline__ u16 f2bf(float f) {  // RNE fp32 -> bf16
  u32 u = __builtin_bit_cast(u32, f);
  u = (u + 0x7fffu + ((u >> 16) & 1u)) >> 16;
  return (u16)u;
}
__device__ __forceinline__ float bf2f(u16 v) {
  u32 u = ((u32)v) << 16;
  return __builtin_bit_cast(float, u);
}
__device__ __forceinline__ u32 pktr(float lo, float hi) {  // trunc-pack 2xfp32->bf16x2
  return __builtin_amdgcn_perm(__builtin_bit_cast(u32, hi),
                               __builtin_bit_cast(u32, lo), 0x07060302u);
}
__device__ __forceinline__ f32x4 mfma16(bf16x8 a, bf16x8 b, f32x4 c) {
  return __builtin_amdgcn_mfma_f32_16x16x32_bf16(a, b, c, 0, 0, 0);
}
__device__ __forceinline__ f32x16 mfma32(bf16x8 a, bf16x8 b, f32x16 c) {
  return __builtin_amdgcn_mfma_f32_32x32x16_bf16(a, b, c, 0, 0, 0);
}
__device__ __forceinline__ f32x16 zero16() {
  f32x16 z = {0,0,0,0,0,0,0,0,0,0,0,0,0,0,0,0};
  return z;
}
__device__ __forceinline__ void store4bf(u16* dst, f32x4 v) {
  u32 lo = (u32)f2bf(v[0]) | ((u32)f2bf(v[1]) << 16);
  u32 hi = (u32)f2bf(v[2]) | ((u32)f2bf(v[3]) << 16);
  *(uint2*)dst = make_uint2(lo, hi);
}

struct MegaArgs {
  const float* mono; const float* cv;
  const float* wsrc[13];
  const float *me_b1, *xe_b1, *mr_b1, *me_b2, *xe_b2;
  const float *mq_b, *mk_b, *mv_b, *xq_b, *xk_b, *xv_b;
  const float *mr_b2, *xr_b, *gamma;
  u16 *wConv, *w1x1, *monoT, *cvT, *m1T, *x1T, *r1T;
  u16 *Qm, *Km, *Vm, *Qx, *Kx, *Vx, *Opart;
  float* lpart;
  float* dout;
};

// shared 3x3 conv body: one wave = 16 out px x 32 out co, 9 taps x 2 MFMAs
__device__ __forceinline__ void conv3x3_body(int bxl, int tid,
    const u16* __restrict__ inT, int Wp, const u16* __restrict__ w9,
    const float* __restrict__ bias, u16* __restrict__ out, int outPitch,
    int outOff, int Ho, int tprShift, int stride) {
  int wid = (bxl * 256 + tid) >> 6;
  int lane = tid & 63, ln = lane & 15, q = lane >> 4;
  int y = wid >> tprShift;
  int x0 = (wid & ((1 << tprShift) - 1)) << 4;
  if (y >= Ho) return;
  f32x4 acc0 = *(const f32x4*)(bias + q * 4);
  f32x4 acc1 = *(const f32x4*)(bias + 16 + q * 4);
  const u16* ib = inT + (stride * y * Wp + stride * (x0 + ln)) * 32 + q * 8;
  const u16* wb = w9 + ln * 32 + q * 8;
#pragma unroll
  for (int dy = 0; dy < 3; ++dy)
#pragma unroll
    for (int dx = 0; dx < 3; ++dx) {
      int tap = dy * 3 + dx;
      bf16x8 bf = *(const bf16x8*)(ib + (dy * Wp + dx) * 32);
      acc0 = mfma16(*(const bf16x8*)(wb + tap * 1024), bf, acc0);
      acc1 = mfma16(*(const bf16x8*)(wb + tap * 1024 + 512), bf, acc1);
    }
#pragma unroll
  for (int r = 0; r < 4; ++r) { acc0[r] = fmaxf(acc0[r], 0.f); acc1[r] = fmaxf(acc1[r], 0.f); }
  u16* ob = out + (outOff + y * outPitch + x0 + ln) * 32;
  store4bf(ob + q * 4, acc0);
  store4bf(ob + 16 + q * 4, acc1);
}

// ============== S0: weight prep + border zeros + transpose ==============
__global__ void __launch_bounds__(256, 8) k_s0(MegaArgs a) {
  __shared__ u16 tr[64][40];
  int t = threadIdx.x, vb = blockIdx.x;
  if (vb < 13) {
    if (vb < 6) {
      const float* s = a.wsrc[vb];
      u16* d = a.wConv + vb * 9216;  // [tap][co][ci]
      for (int i = t; i < 9216; i += 256) {
        int tap = i >> 10, co = (i >> 5) & 31, ci = i & 31;
        d[i] = f2bf(s[co * 288 + ci * 9 + tap]);
      }
    } else {
      const float* s = a.wsrc[vb];
      u16* d = a.w1x1 + (vb - 6) * 1024;
      for (int i = t; i < 1024; i += 256) d[i] = f2bf(s[i]);
    }
    return;
  }
  if (vb < 138) {
    int zb = vb - 13;
    int buf = zb % 5, blk = zb / 5;
    u16* b; int Hp, Wp;
    switch (buf) {
      case 0: b = a.monoT; Hp = 258; Wp = 514; break;
      case 1: b = a.cvT;   Hp = 258; Wp = 514; break;
      case 2: b = a.m1T;   Hp = 130; Wp = 258; break;
      case 3: b = a.x1T;   Hp = 130; Wp = 258; break;
      default: b = a.r1T;  Hp = 258; Wp = 514; break;
    }
    int id = blk * 256 + t;
    int cell = id >> 2, c8 = (id & 3) << 3;
    if (cell < 2 * (Hp + Wp)) {
      int r, c;
      if (cell < Wp)               { r = 0;                  c = cell; }
      else if (cell < 2 * Wp)      { r = Hp - 1;             c = cell - Wp; }
      else if (cell < 2 * Wp + Hp) { r = cell - 2 * Wp;      c = 0; }
      else                         { r = cell - 2 * Wp - Hp; c = Wp - 1; }
      bf16x8 z = {0, 0, 0, 0, 0, 0, 0, 0};
      *(bf16x8*)&b[(r * Wp + c) * 32 + c8] = z;
    }
    return;
  }
  int idx = vb - 138;
  int xb = idx & 7, y = (idx >> 3) & 255, z = idx >> 11;
  const float* src = z ? a.cv : a.mono;
  u16* dst = z ? a.cvT : a.monoT;
  int x0 = xb << 6;
  int ci = t >> 3, kx = (t & 7) << 3;
  const float* sp = src + ci * 131072 + y * 512 + x0 + kx;
  float4 p = *(const float4*)sp;
  float4 p2 = *(const float4*)(sp + 4);
  tr[kx + 0][ci] = f2bf(p.x);  tr[kx + 1][ci] = f2bf(p.y);
  tr[kx + 2][ci] = f2bf(p.z);  tr[kx + 3][ci] = f2bf(p.w);
  tr[kx + 4][ci] = f2bf(p2.x); tr[kx + 5][ci] = f2bf(p2.y);
  tr[kx + 6][ci] = f2bf(p2.z); tr[kx + 7][ci] = f2bf(p2.w);
  __syncthreads();
  int x = t >> 2, c8 = (t & 3) << 3;
  bf16x8 v = *(bf16x8*)&tr[x][c8];
  *(bf16x8*)(dst + ((y + 1) * 514 + (x0 + x + 1)) * 32 + c8) = v;
}

// ============== S1: three big convs ==============
__global__ void __launch_bounds__(256, 8) k_s1(MegaArgs a) {
  int t = threadIdx.x, vb = blockIdx.x;
  if (vb < 512)
    conv3x3_body(vb, t, a.monoT, 514, a.wConv + 0 * 9216, a.me_b1, a.m1T, 258, 259, 128, 4, 2);
  else if (vb < 1024)
    conv3x3_body(vb - 512, t, a.cvT, 514, a.wConv + 2 * 9216, a.xe_b1, a.x1T, 258, 259, 128, 4, 2);
  else
    conv3x3_body(vb - 1024, t, a.monoT, 514, a.wConv + 4 * 9216, a.mr_b1, a.r1T, 514, 515, 256, 5, 1);
}

// ============== S2: feat conv + q/k/v projections ==============
__global__ void __launch_bounds__(256, 8) k_s2(MegaArgs a) {
  __shared__ u16 fp[4][16][40];
  int t = threadIdx.x, vb = blockIdx.x;
  int branch = vb >> 7;
  int bxl = vb & 127;
  const u16* inT = branch ? a.x1T : a.m1T;
  const u16* w9 = a.wConv + (branch ? 3 : 1) * 9216;
  const float* cb = branch ? a.xe_b2 : a.me_b2;
  int wave = t >> 6, lane = t & 63, ln = lane & 15, q = lane >> 4;
  int wid = bxl * 4 + wave;
  int y = wid >> 3, x0 = (wid & 7) << 4;
  f32x4 acc0 = *(const f32x4*)(cb + q * 4);
  f32x4 acc1 = *(const f32x4*)(cb + 16 + q * 4);
  const u16* ib = inT + (2 * y * 258 + 2 * (x0 + ln)) * 32 + q * 8;
  const u16* wb = w9 + ln * 32 + q * 8;
#pragma unroll
  for (int dy = 0; dy < 3; ++dy)
#pragma unroll
    for (int dx = 0; dx < 3; ++dx) {
      int tap = dy * 3 + dx;
      bf16x8 bf = *(const bf16x8*)(ib + (dy * 258 + dx) * 32);
      acc0 = mfma16(*(const bf16x8*)(wb + tap * 1024), bf, acc0);
      acc1 = mfma16(*(const bf16x8*)(wb + tap * 1024 + 512), bf, acc1);
    }
#pragma unroll
  for (int r = 0; r < 4; ++r) { acc0[r] = fmaxf(acc0[r], 0.f); acc1[r] = fmaxf(acc1[r], 0.f); }
  u16* fpw = &fp[wave][0][0];
  store4bf(fpw + ln * 40 + q * 4, acc0);
  store4bf(fpw + ln * 40 + 16 + q * 4, acc1);
  bf16x8 bfrag = *(const bf16x8*)(fpw + ln * 40 + q * 8);  // same-wave RAW via lgkmcnt
  int p0 = wid * 16;
  const float* qb = branch ? a.xq_b : a.mq_b;
  const float* kb = branch ? a.xk_b : a.mk_b;
  const float* vbias = branch ? a.xv_b : a.mv_b;
  u16* Qd = branch ? a.Qx : a.Qm;
  u16* Kd = branch ? a.Kx : a.Km;
  u16* Vd = branch ? a.Vx : a.Vm;
  int wbase = branch * 3;
#pragma unroll
  for (int pj3 = 0; pj3 < 3; ++pj3) {
    const u16* w = a.w1x1 + (wbase + pj3) * 1024;
    const float* bias = pj3 == 0 ? qb : (pj3 == 1 ? kb : vbias);
    bf16x8 wa0 = *(const bf16x8*)(w + ln * 32 + q * 8);
    bf16x8 wa1 = *(const bf16x8*)(w + (16 + ln) * 32 + q * 8);
    f32x4 c0 = *(const f32x4*)(bias + q * 4);
    f32x4 c1 = *(const f32x4*)(bias + 16 + q * 4);
    c0 = mfma16(wa0, bfrag, c0);
    c1 = mfma16(wa1, bfrag, c1);
    if (pj3 == 0) {
#pragma unroll
      for (int r = 0; r < 4; ++r) { c0[r] *= 1.4426950408889634f; c1[r] *= 1.4426950408889634f; }
    }
    if (pj3 < 2) {
      u16* dst = pj3 == 0 ? Qd : Kd;
      store4bf(dst + (p0 + ln) * 32 + q * 4, c0);
      store4bf(dst + (p0 + ln) * 32 + 16 + q * 4, c1);
    } else {
      int p = p0 + ln;
      int jl = p & 63, jb = p & ~63;
      int pj = jb + (jl >> 5) * 32 + ((jl >> 4) & 1) * 16 + ((jl >> 2) & 1) * 8
             + ((jl >> 3) & 1) * 4 + (jl & 3);
#pragma unroll
      for (int r = 0; r < 4; ++r) {
        Vd[(q * 4 + r) * 8192 + pj] = f2bf(c0[r]);
        Vd[(16 + q * 4 + r) * 8192 + pj] = f2bf(c1[r]);
      }
    }
  }
}

// ============== S3: split-j flash attention ==============
__global__ void __launch_bounds__(256, 4) k_s3(MegaArgs a) {
  __shared__ struct { u16 Kl[2][64][40]; u16 Vl[2][32][72]; } lds;
  int t = threadIdx.x, vb = blockIdx.x;
  int ib64 = vb & 63, sp = (vb >> 6) & 7, att = vb >> 9;
  const u16 *Qp, *Kp, *Vp;
  if (att == 0) { Qp = a.Qm; Kp = a.Km; Vp = a.Vx; }
  else          { Qp = a.Qx; Kp = a.Kx; Vp = a.Vm; }
  int j0 = sp << 10;
  int wave = t >> 6, lane = t & 63, ln = lane & 31, h = lane >> 5;
  int iw = ib64 * 128 + wave * 32;
  bf16x8 qf0 = *(const bf16x8*)(Qp + (iw + ln) * 32 + h * 8);
  bf16x8 qf1 = *(const bf16x8*)(Qp + (iw + ln) * 32 + 16 + h * 8);
  int krow = t >> 2, kcol = (t & 3) << 3;
  int vrow = t >> 3, vcol = (t & 7) << 3;
  const u16* Kg = Kp + j0 * 32;
  const u16* Vg = Vp + j0;
  bf16x8 kn = *(const bf16x8*)(Kg + t * 8);
  bf16x8 vn = *(const bf16x8*)(Vg + vrow * 8192 + vcol);
  *(bf16x8*)&lds.Kl[0][krow][kcol] = kn;
  *(bf16x8*)&lds.Vl[0][vrow][vcol] = vn;
  f32x16 O = zero16(), lac = zero16();
  const short oneb = 0x3F80;
  const bf16x8 ones = {oneb, oneb, oneb, oneb, oneb, oneb, oneb, oneb};
  for (int jt = 0; jt < 16; ++jt) {
    __syncthreads();
    bool have = (jt + 1) < 16;
    if (have) {
      kn = *(const bf16x8*)(Kg + (jt + 1) * 2048 + t * 8);
      vn = *(const bf16x8*)(Vg + vrow * 8192 + (jt + 1) * 64 + vcol);
    }
    int cur = jt & 1;
    f32x16 s0 = mfma32(*(const bf16x8*)&lds.Kl[cur][ln][h * 8], qf0, zero16());
    s0 = mfma32(*(const bf16x8*)&lds.Kl[cur][ln][16 + h * 8], qf1, s0);
    f32x16 s1 = mfma32(*(const bf16x8*)&lds.Kl[cur][32 + ln][h * 8], qf0, zero16());
    s1 = mfma32(*(const bf16x8*)&lds.Kl[cur][32 + ln][16 + h * 8], qf1, s1);
    float e0[16], e1[16];
#pragma unroll
    for (int r = 0; r < 16; ++r) {
      e0[r] = __builtin_amdgcn_exp2f(s0[r]);
      e1[r] = __builtin_amdgcn_exp2f(s1[r]);
    }
    union PF { bf16x8 v; u32 w[4]; } pf[4];
#pragma unroll
    for (int t2 = 0; t2 < 4; ++t2) {
      int base = (t2 & 1) * 8;
      if (t2 < 2) {
#pragma unroll
        for (int p = 0; p < 4; ++p) pf[t2].w[p] = pktr(e0[base + 2 * p], e0[base + 2 * p + 1]);
      } else {
#pragma unroll
        for (int p = 0; p < 4; ++p) pf[t2].w[p] = pktr(e1[base + 2 * p], e1[base + 2 * p + 1]);
      }
    }
#pragma unroll
    for (int t2 = 0; t2 < 4; ++t2) {
      bf16x8 vf = *(const bf16x8*)&lds.Vl[cur][ln][t2 * 16 + h * 8];
      O = mfma32(pf[t2].v, vf, O);
      lac = mfma32(pf[t2].v, ones, lac);
    }
    if (have) {
      *(bf16x8*)&lds.Kl[1 - cur][krow][kcol] = kn;
      *(bf16x8*)&lds.Vl[1 - cur][vrow][vcol] = vn;
    }
  }
  u16* ob = a.Opart + (size_t)(att * 8 + sp) * 262144;
  float* lb = a.lpart + (att * 8 + sp) * 8192;
#pragma unroll
  for (int r = 0; r < 16; ++r) {
    int ig = iw + (r & 3) + 8 * (r >> 2) + 4 * h;
    ob[ig * 32 + ln] = f2bf(O[r]);
    if (ln == 0) lb[ig] = lac[r];
  }
}

// ============== S4: split merge + final epilogues ==============
__global__ void __launch_bounds__(256, 8) k_s4(MegaArgs a) {
  __shared__ float fin[16][32];
  int t = threadIdx.x, u = blockIdx.x;
  int half = u >> 9;
  int tile = u & 511;
  int tx = tile & 7, ty = tile >> 3;
  int rbase = ty * 128 + tx * 16;
  for (int e = t; e < 512; e += 256) {
    int ir = e >> 5, ch = e & 31;
    int gr = rbase + ir;
    float os = 0.f, ls = 0.f;
#pragma unroll
    for (int sp = 0; sp < 8; ++sp) {
      os += bf2f(a.Opart[(size_t)(half * 8 + sp) * 262144 + gr * 32 + ch]);
      ls += a.lpart[(half * 8 + sp) * 8192 + gr];
    }
    fin[ir][ch] = os / ls;
  }
  __syncthreads();
  int wave = t >> 6, lane = t & 63, ln = lane & 15, q = lane >> 4;
  int y = ty * 4 + wave;
  float g = a.gamma[0];
  if (half == 0) {
    const u16* wb = a.wConv + 5 * 9216 + ln * 32 + q * 8;
    f32x4 b0 = *(const f32x4*)(a.mr_b2 + q * 4);
    f32x4 b1 = *(const f32x4*)(a.mr_b2 + 16 + q * 4);
#pragma unroll
    for (int xc = 0; xc < 4; ++xc) {
      int x0 = tx * 64 + xc * 16;
      f32x4 acc0 = b0, acc1 = b1;
      const u16* ib = a.r1T + (y * 514 + x0 + ln) * 32 + q * 8;
#pragma unroll
      for (int dy = 0; dy < 3; ++dy)
#pragma unroll
        for (int dx = 0; dx < 3; ++dx) {
          int tap = dy * 3 + dx;
          bf16x8 bf = *(const bf16x8*)(ib + (dy * 514 + dx) * 32);
          acc0 = mfma16(*(const bf16x8*)(wb + tap * 1024), bf, acc0);
          acc1 = mfma16(*(const bf16x8*)(wb + tap * 1024 + 512), bf, acc1);
        }
      const float* ap = fin[xc * 4 + (ln >> 2)];
      float* ob = a.dout + y * 512 + x0 + ln;
#pragma unroll
      for (int r = 0; r < 4; ++r) {
        int co0 = q * 4 + r, co1 = 16 + q * 4 + r;
        ob[co0 * 131072] = fmaxf(acc0[r], 0.f) + g * ap[co0];
        ob[co1 * 131072] = fmaxf(acc1[r], 0.f) + g * ap[co1];
      }
    }
  } else {
    const u16* w = a.w1x1 + 6 * 1024;
    bf16x8 wa0 = *(const bf16x8*)(w + ln * 32 + q * 8);
    bf16x8 wa1 = *(const bf16x8*)(w + (16 + ln) * 32 + q * 8);
    f32x4 b0 = *(const f32x4*)(a.xr_b + q * 4);
    f32x4 b1 = *(const f32x4*)(a.xr_b + 16 + q * 4);
#pragma unroll
    for (int xc = 0; xc < 4; ++xc) {
      int x0 = tx * 64 + xc * 16;
      bf16x8 bf = *(const bf16x8*)(a.cvT + ((y + 1) * 514 + x0 + ln + 1) * 32 + q * 8);
      f32x4 c0 = mfma16(wa0, bf, b0);
      f32x4 c1 = mfma16(wa1, bf, b1);
      const float* ap = fin[xc * 4 + (ln >> 2)];
      float* ob = a.dout + 32 * 131072 + y * 512 + x0 + ln;
#pragma unroll
      for (int r = 0; r < 4; ++r) {
        int co0 = q * 4 + r, co1 = 16 + q * 4 + r;
        ob[co0 * 131072] = fmaxf(c0[r], 0.f) + g * ap[co0];
        ob[co1 * 131072] = fmaxf(c1[r], 0.f) + g * ap[co1];
      }
    }
  }
}

extern "C" void kernel_launch(void* const* d_in, const int* in_sizes, int n_in,
                              void* d_out, int out_size, void* d_ws, size_t ws_size,
                              hipStream_t stream) {
  char* ws = (char*)d_ws;
  MegaArgs m;
  m.mono  = (const float*)d_in[0];
  m.cv    = (const float*)d_in[1];
  m.wsrc[0] = (const float*)d_in[2];   // me_w1
  m.wsrc[1] = (const float*)d_in[4];   // me_w2
  m.wsrc[2] = (const float*)d_in[6];   // xe_w1
  m.wsrc[3] = (const float*)d_in[8];   // xe_w2
  m.wsrc[4] = (const float*)d_in[22];  // mr_w1
  m.wsrc[5] = (const float*)d_in[24];  // mr_w2
  m.wsrc[6] = (const float*)d_in[10];  // mq_w
  m.wsrc[7] = (const float*)d_in[12];  // mk_w
  m.wsrc[8] = (const float*)d_in[14];  // mv_w
  m.wsrc[9] = (const float*)d_in[16];  // xq_w
  m.wsrc[10] = (const float*)d_in[18]; // xk_w
  m.wsrc[11] = (const float*)d_in[20]; // xv_w
  m.wsrc[12] = (const float*)d_in[26]; // xr_w
  m.me_b1 = (const float*)d_in[3];
  m.me_b2 = (const float*)d_in[5];
  m.xe_b1 = (const float*)d_in[7];
  m.xe_b2 = (const float*)d_in[9];
  m.mq_b  = (const float*)d_in[11];
  m.mk_b  = (const float*)d_in[13];
  m.mv_b  = (const float*)d_in[15];
  m.xq_b  = (const float*)d_in[17];
  m.xk_b  = (const float*)d_in[19];
  m.xv_b  = (const float*)d_in[21];
  m.mr_b1 = (const float*)d_in[23];
  m.mr_b2 = (const float*)d_in[25];
  m.xr_b  = (const float*)d_in[27];
  m.gamma = (const float*)d_in[28];
  m.wConv = (u16*)(ws + 0);          // 6 * [9][32][32] bf16
  m.w1x1  = (u16*)(ws + 110592);     // 7 * [32][32] bf16
  m.monoT = (u16*)(ws + 124928);     // [258][514][32] bf16 (dead after S1)
  m.Opart = (u16*)(ws + 124928);     // [2][8][8192][32] bf16 — aliases monoT
  m.cvT   = (u16*)(ws + 8612096);    // [258][514][32]
  m.m1T   = (u16*)(ws + 17099264);   // [130][258][32]
  m.x1T   = (u16*)(ws + 19245824);
  m.r1T   = (u16*)(ws + 21392384);   // [258][514][32]
  m.Qm    = (u16*)(ws + 30928128);   // [8192][32]
  m.Km    = (u16*)(ws + 31452416);
  m.Vm    = (u16*)(ws + 31976704);   // [32][8192] pi-permuted
  m.Qx    = (u16*)(ws + 32500992);
  m.Kx    = (u16*)(ws + 33025280);
  m.Vx    = (u16*)(ws + 33549568);
  m.lpart = (float*)(ws + 36171008); // [2][8][8192] fp32
  m.dout  = (float*)d_out;

  k_s0<<<4234, 256, 0, stream>>>(m);
  k_s1<<<3072, 256, 0, stream>>>(m);
  k_s2<<<256,  256, 0, stream>>>(m);
  k_s3<<<1024, 256, 0, stream>>>(m);
  k_s4<<<1024, 256, 0, stream>>>(m);
}